// Round 1
// 739.899 us; speedup vs baseline: 1.3524x; 1.3524x over previous
//
#include <hip/hip_runtime.h>

// ---------------------------------------------------------------------------
// ConvUnrolledISTAEncoder on MI355X (gfx950)
// B=16, CIN=1, T=262144, A=128, K=16 (stride==kernel), ITERS=8, NCLS=3
// Columns: N = B*Tp = 262144 (Tp = 16384). Per column:
//   h_x = Wx @ x_taps + bx            (K=16 conv -> MFMA with zero-padded K)
//   8x:  h = relu(h_x + Wh @ h)       (128x128 matvec per column)
//   out = [softplus(Wk h+bk)+eps ; softplus(Wt h+bt)+eps ; Wp h + bp]
// Round-1 polish vs previous best (502 us/dispatch):
//   * Wh fragment table moved VGPRs(128) -> block-shared LDS (32 KB): unified
//     VGPR+AGPR drops ~200 -> ~100, occupancy 2 -> 3 waves/SIMD (LDS-capped
//     at 3 blocks/CU: 50.2 KB/block).
//   * all f32->bf16 via v_cvt_pk_bf16_f32 (2 elems/instr) instead of manual
//     RNE bit-twiddle (+pack) -- cuts ISTA-loop VALU ~3x.
//   * softplus via native v_exp/v_log (__expf/__logf) instead of log1pf
//     libcall (~35 ops -> ~6 ops, err ~1e-6).
//   * epilogue row-tiles interleaved rt = rti*4+w so softplus cost is spread
//     evenly over the 4 waves (was: waves 0/1 own all transcendentals).
// ---------------------------------------------------------------------------

typedef __attribute__((ext_vector_type(8))) short short8;   // 8 x bf16
typedef __attribute__((ext_vector_type(2))) unsigned uint2v;
typedef __attribute__((ext_vector_type(4))) float float4v;  // MFMA C/D

#define TP 16384
#define THETA_OFF 33554432u   // 16*128*16384
#define LOGIT_OFF 67108864u   // 2*THETA_OFF

// ws layout (bf16 elements):
//  [0      , 16384): Whf  - Wh A-frags:  frag f=(mt*4+ks), elem (f*64+lane)*8+j
//  [16384  , 20480): Wxf  - Wx A-frags (K padded 16->32 with zeros): f=mt
//  [20480  ,102400): Wcf  - [Wk;Wt;Wp] A-frags: f=(rt*4+ks), rt in [0,40)
#define WS_WXF 16384
#define WS_WCF 20480
#define WS_TOTAL 102400

__device__ __forceinline__ short f2bf(float f) {
  union { float f; unsigned u; } v; v.f = f;
  unsigned r = (v.u + 0x7fffu + ((v.u >> 16) & 1u)) >> 16;  // RNE
  return (short)r;
}

// packed f32x2 -> bf16x2 (RNE), single VALU op; no builtin on gfx950
__device__ __forceinline__ unsigned cvt_pk_bf16(float a, float b) {
  unsigned r;
  asm("v_cvt_pk_bf16_f32 %0, %1, %2" : "=v"(r) : "v"(a), "v"(b));
  return r;
}

__global__ void prep_kernel(const float* __restrict__ Wx, const float* __restrict__ Wh,
                            const float* __restrict__ Wk, const float* __restrict__ Wt,
                            const float* __restrict__ Wp, short* __restrict__ wsbf) {
  int i = blockIdx.x * 256 + threadIdx.x;
  if (i >= WS_TOTAL) return;
  float val;
  if (i < WS_WXF) {                       // Wh fragments
    int e = i, f = e >> 9, lane = (e >> 3) & 63, j = e & 7;
    int mt = f >> 2, ks = f & 3, q = lane >> 4, r = lane & 15;
    val = Wh[(mt * 16 + r) * 128 + ks * 32 + q * 8 + j];
  } else if (i < WS_WCF) {                // Wx fragments (zero-pad k>=16)
    int e = i - WS_WXF, mt = e >> 9, lane = (e >> 3) & 63, j = e & 7;
    int q = lane >> 4, r = lane & 15;
    val = (q < 2) ? Wx[(mt * 16 + r) * 16 + q * 8 + j] : 0.0f;
  } else {                                // [Wk;Wt;Wp] fragments
    int e = i - WS_WCF, f = e >> 9, lane = (e >> 3) & 63, j = e & 7;
    int rt = f >> 2, ks = f & 3, q = lane >> 4, r = lane & 15;
    int m = rt * 16 + r, k = ks * 32 + q * 8 + j;
    if (rt < 8)       val = Wk[m * 128 + k];
    else if (rt < 16) val = Wt[(m - 128) * 128 + k];
    else              val = Wp[(m - 256) * 128 + k];
  }
  wsbf[i] = f2bf(val);
}

__global__ __launch_bounds__(256, 3) void ista_kernel(
    const float* __restrict__ x,  const float* __restrict__ bx,
    const float* __restrict__ bk, const float* __restrict__ bt,
    const float* __restrict__ bp, const short* __restrict__ wsbf,
    float* __restrict__ out) {
  // Wh fragment table, shared by the block's 4 waves (was 128 VGPRs/wave).
  __shared__ short WhLds[16384];            // 32 KB
  // H in LDS: [64 cols][136] bf16 (stride 136 keeps rows 16B-aligned, breaks
  // the power-of-2 bank stride). Wave w owns cols [w*16, w*16+16) -> the
  // ISTA-loop LDS traffic is wave-private; no __syncthreads needed there.
  __shared__ short Hlds[64 * 136];          // 17.4 KB

  const int tid  = threadIdx.x;
  const int w    = tid >> 6;
  const int lane = tid & 63;
  const int q    = lane >> 4;
  const int r    = lane & 15;
  const int g0   = blockIdx.x << 6;     // first global column of block
  const int b    = g0 >> 14;            // batch (64 | 16384, so no straddle)
  const int t0   = g0 & (TP - 1);
  const int col_local = (w << 4) + r;   // this lane's column within block

  // --- stage Wh frag table into LDS (linear 32 KB copy, coalesced b128) ----
  {
    const short8* src = (const short8*)wsbf;
    short8* dst = (short8*)WhLds;
#pragma unroll
    for (int k2 = 0; k2 < 8; ++k2) dst[(k2 << 8) + tid] = src[(k2 << 8) + tid];
  }

  // --- x B-fragment: column (g0+col_local) taps 0..15, K padded to 32 ------
  short8 xfrag;
  {
    union { short8 s; unsigned u[4]; } xu;
    xu.u[0] = xu.u[1] = xu.u[2] = xu.u[3] = 0u;
    if (q < 2) {
      const float* xp = x + (((size_t)(g0 + col_local)) << 4) + (q << 3);
      xu.u[0] = cvt_pk_bf16(xp[0], xp[1]);
      xu.u[1] = cvt_pk_bf16(xp[2], xp[3]);
      xu.u[2] = cvt_pk_bf16(xp[4], xp[5]);
      xu.u[3] = cvt_pk_bf16(xp[6], xp[7]);
    }
    xfrag = xu.s;
  }

  // --- h_x = Wx @ x + bx, fp32 fragments (C-seed for every iteration) ------
  const short8* wxfp = (const short8*)(wsbf + WS_WXF);
  float4v hx[8];
#pragma unroll
  for (int mt = 0; mt < 8; ++mt) {
    float4v c = *(const float4v*)(bx + (mt << 4) + (q << 2));
    hx[mt] = __builtin_amdgcn_mfma_f32_16x16x32_bf16(wxfp[(mt << 6) + lane], xfrag, c, 0, 0, 0);
  }

  // --- iteration 1: h = relu(h_x) ------------------------------------------
  short* hrow = &Hlds[col_local * 136];
#pragma unroll
  for (int mt = 0; mt < 8; ++mt) {
    uint2v v2;
    v2[0] = cvt_pk_bf16(fmaxf(hx[mt][0], 0.0f), fmaxf(hx[mt][1], 0.0f));
    v2[1] = cvt_pk_bf16(fmaxf(hx[mt][2], 0.0f), fmaxf(hx[mt][3], 0.0f));
    *(uint2v*)(hrow + (mt << 4) + (q << 2)) = v2;
  }

  __syncthreads();  // WhLds staged (H writes above are wave-private)

  // --- iterations 2..8: h = relu(h_x + Wh h), A-frags streamed from LDS ----
  const char* whb = (const char*)WhLds;
  int wboff = lane << 4;                // byte offset of this lane in a frag
  for (int it = 1; it < 8; ++it) {
    // launder the base each iteration so LICM can't hoist the 32 ds_reads
    // back into 128 registers (which would undo the occupancy win)
    asm("" : "+v"(wboff));
    short8 Bf[4];
#pragma unroll
    for (int ks = 0; ks < 4; ++ks)
      Bf[ks] = *(const short8*)(hrow + (ks << 5) + (q << 3));  // ds_read_b128
#pragma unroll
    for (int mt = 0; mt < 8; ++mt) {
      float4v c = hx[mt];
#pragma unroll
      for (int ks = 0; ks < 4; ++ks) {
        const short8 A = *(const short8*)(whb + ((((mt << 2) + ks) << 10)) + wboff);
        c = __builtin_amdgcn_mfma_f32_16x16x32_bf16(A, Bf[ks], c, 0, 0, 0);
      }
      uint2v v2;
      v2[0] = cvt_pk_bf16(fmaxf(c[0], 0.0f), fmaxf(c[1], 0.0f));
      v2[1] = cvt_pk_bf16(fmaxf(c[2], 0.0f), fmaxf(c[3], 0.0f));
      *(uint2v*)(hrow + (mt << 4) + (q << 2)) = v2;            // ds_write_b64
    }
  }

  __syncthreads();  // output phase reads all 64 columns

  // --- B-fragments for ALL 64 cols (16 frags = 64 VGPRs) -------------------
  short8 Ball[16];
#pragma unroll
  for (int nt = 0; nt < 4; ++nt)
#pragma unroll
    for (int ks = 0; ks < 4; ++ks)
      Ball[(nt << 2) + ks] =
          *(const short8*)&Hlds[((nt << 4) + r) * 136 + (ks << 5) + (q << 3)];

  // --- output projection: row-tiles interleaved rt = rti*4 + w -------------
  // rti 0..1 -> Wk (softplus), 2..3 -> Wt (softplus), 4..9 -> Wp (logits);
  // every wave gets the same mix -> no inter-wave imbalance.
  const short8* wcfp = (const short8*)(wsbf + WS_WCF);
  const size_t brow = ((size_t)b) << 7;  // b*128

  for (int rti = 0; rti < 10; ++rti) {
    const int rt = (rti << 2) + w;       // row-tile of 16 rows
    short8 Af[4];
#pragma unroll
    for (int ks = 0; ks < 4; ++ks) Af[ks] = wcfp[(((rt << 2) + ks) << 6) + lane];
    const int grb = (rt << 4) + (q << 2);
    float4v bias;
    if (rti < 2)      bias = *(const float4v*)(bk + grb);
    else if (rti < 4) bias = *(const float4v*)(bt + grb - 128);
    else              bias = *(const float4v*)(bp + grb - 256);

#pragma unroll
    for (int nt = 0; nt < 4; ++nt) {
      float4v c = {0.0f, 0.0f, 0.0f, 0.0f};
#pragma unroll
      for (int ks = 0; ks < 4; ++ks)
        c = __builtin_amdgcn_mfma_f32_16x16x32_bf16(Af[ks], Ball[(nt << 2) + ks], c, 0, 0, 0);
      const int t = t0 + (nt << 4) + r;

      if (rti < 4) {
        // softplus(v) + eps via native v_exp/v_log (err ~1e-6, band is 3e-2)
        const size_t off  = (rti < 2) ? (size_t)0 : (size_t)THETA_OFF;
        const int    arow = (rti < 2) ? grb : grb - 128;
        float* po = out + off + ((brow + (size_t)arow) << 14) + (size_t)t;
#pragma unroll
        for (int g = 0; g < 4; ++g) {
          const float v  = c[g] + bias[g];
          const float sp = fmaxf(v, 0.0f) + __logf(1.0f + __expf(-fabsf(v))) + 1e-4f;
          po[(size_t)g << 14] = sp;
        }
      } else {
        const unsigned o0  = (unsigned)(grb - 256);
        const unsigned a0  = o0 / 3u;          // magic-div, once per (rti,lane)
        const unsigned rem = o0 - a0 * 3u;
#pragma unroll
        for (int g = 0; g < 4; ++g) {
          const float v = c[g] + bias[g];
          const unsigned cc  = rem + (unsigned)g;     // 0..5
          const unsigned adj = (cc >= 3u) ? 1u : 0u;  // at most one carry
          const unsigned a   = a0 + adj;
          const unsigned ci  = cc - adj * 3u;
          out[(size_t)LOGIT_OFF + ((((brow + (size_t)a) << 14) + (size_t)t) * 3u) + ci] = v;
        }
      }
    }
  }
}

extern "C" void kernel_launch(void* const* d_in, const int* in_sizes, int n_in,
                              void* d_out, int out_size, void* d_ws, size_t ws_size,
                              hipStream_t stream) {
  const float* x  = (const float*)d_in[0];
  const float* Wx = (const float*)d_in[1];
  const float* bx = (const float*)d_in[2];
  const float* Wh = (const float*)d_in[3];
  const float* Wk = (const float*)d_in[4];
  const float* bk = (const float*)d_in[5];
  const float* Wt = (const float*)d_in[6];
  const float* bt = (const float*)d_in[7];
  const float* Wp = (const float*)d_in[8];
  const float* bp = (const float*)d_in[9];
  short* wsbf = (short*)d_ws;
  float* out  = (float*)d_out;

  // ws re-poisoned before every call -> rebuild bf16 fragment tables each time
  hipLaunchKernelGGL(prep_kernel, dim3(WS_TOTAL / 256), dim3(256), 0, stream,
                     Wx, Wh, Wk, Wt, Wp, wsbf);
  // 262144 cols / 64 per block
  hipLaunchKernelGGL(ista_kernel, dim3(4096), dim3(256), 0, stream,
                     x, bx, bk, bt, bp, wsbf, out);
}